// Round 2
// baseline (1135.817 us; speedup 1.0000x reference)
//
#include <hip/hip_runtime.h>
#include <cstdint>
#include <cstddef>

typedef _Float16 half8 __attribute__((ext_vector_type(8)));
typedef _Float16 half4v __attribute__((ext_vector_type(4)));
typedef float f32x4 __attribute__((ext_vector_type(4)));

__device__ __forceinline__ float shrinkf(float v, float eta) {
  float a = fabsf(v) - eta;            // LAMBD = 1.0
  return a > 0.0f ? copysignf(a, v) : 0.0f;
}

// ---------- table builders (verified in R1) ----------
// Wa[n=2p+c][k=2q+d], 512 x 256 fp16
__global__ void build_wa(const float* __restrict__ A, _Float16* __restrict__ Wa) {
  int idx = blockIdx.x * 256 + threadIdx.x;     // 131072
  int n = idx >> 8, k = idx & 255;
  int p = n >> 1, c = n & 1, q = k >> 1, d = k & 1;
  const float* A0 = A;
  const float* A1 = A + 256 * 128;
  float v;
  if (c == 0) v = (d == 0) ? A0[p * 128 + q] : -A1[p * 128 + q];
  else        v = (d == 0) ? A1[p * 128 + q] :  A0[p * 128 + q];
  Wa[idx] = (_Float16)v;
}

// Wc_t = realify(I - g_t * B), 10 tables of 512 x 512 fp16
__global__ void build_wc(const float* __restrict__ B, const float* __restrict__ gammas,
                         _Float16* __restrict__ Wc) {
  int idx = blockIdx.x * 256 + threadIdx.x;     // 2,621,440
  int t = idx >> 18;
  int r = idx & 262143;
  int n = r >> 9, k = r & 511;
  int p = n >> 1, c = n & 1, q = k >> 1, d = k & 1;
  float g = gammas[t + 1];
  const float* B0 = B;
  const float* B1 = B + 256 * 256;
  float eye = (p == q) ? 1.0f : 0.0f;
  float v;
  if (c == 0) v = (d == 0) ? (eye - g * B0[p * 256 + q]) : ( g * B1[p * 256 + q]);
  else        v = (d == 0) ? (     - g * B1[p * 256 + q]) : (eye - g * B0[p * 256 + q]);
  Wc[idx] = (_Float16)v;
}

// ---------- fused GEMM phase ----------
// Wave computes 128 out-cols (A-operand = W rows, global) x 64 batch rows
// (B-operand = X, LDS). acc[im][jn]: im = m-frag (out-col/16), jn = n-frag (row/16).
// C/D layout: col(n)=lane&15 = batch row, row(m)=(lane>>4)*4+reg = out-col.
template <int NKS, int LDW>
__device__ __forceinline__ void gemm_phase(const _Float16* __restrict__ W,
                                           const _Float16* sX,
                                           int wave, int l16, int quad,
                                           f32x4 (&acc)[8][4]) {
  half8 wfA[8], wfB[8];
  const _Float16* wp = W + (size_t)(wave * 128 + l16) * LDW + quad * 8;
#pragma unroll
  for (int im = 0; im < 8; ++im)
    wfA[im] = *(const half8*)(wp + im * 16 * LDW);
#pragma unroll
  for (int ks = 0; ks < NKS; ks += 2) {
    half8 xf[4];
#pragma unroll
    for (int jn = 0; jn < 4; ++jn) {
      int row = jn * 16 + l16;
      int phys = (ks * 4 + quad) ^ (row & 7);       // XOR chunk swizzle
      xf[jn] = *(const half8*)(sX + row * 512 + phys * 8);
    }
#pragma unroll
    for (int im = 0; im < 8; ++im)                  // prefetch next W frags
      wfB[im] = *(const half8*)(wp + im * 16 * LDW + (ks + 1) * 32);
#pragma unroll
    for (int im = 0; im < 8; ++im)
#pragma unroll
      for (int jn = 0; jn < 4; ++jn)
        acc[im][jn] = __builtin_amdgcn_mfma_f32_16x16x32_f16(wfA[im], xf[jn], acc[im][jn], 0, 0, 0);
#pragma unroll
    for (int jn = 0; jn < 4; ++jn) {
      int row = jn * 16 + l16;
      int phys = ((ks + 1) * 4 + quad) ^ (row & 7);
      xf[jn] = *(const half8*)(sX + row * 512 + phys * 8);
    }
    if (ks + 2 < NKS) {
#pragma unroll
      for (int im = 0; im < 8; ++im)
        wfA[im] = *(const half8*)(wp + im * 16 * LDW + (ks + 2) * 32);
    }
#pragma unroll
    for (int im = 0; im < 8; ++im)
#pragma unroll
      for (int jn = 0; jn < 4; ++jn)
        acc[im][jn] = __builtin_amdgcn_mfma_f32_16x16x32_f16(wfB[im], xf[jn], acc[im][jn], 0, 0, 0);
  }
}

// ---------- the fused LISTA kernel ----------
// Block = 256 threads (4 waves), owns 64 batch rows. X lives in LDS (64 KB)
// across all iterations. Only 2 barriers per iteration, none in the K-loop.
__global__ __launch_bounds__(256, 2) void lista_fused(
    const float* __restrict__ y,
    const _Float16* __restrict__ Wa,
    const _Float16* __restrict__ Wc,
    _Float16* __restrict__ AyBuf,
    float* __restrict__ out,
    const float* __restrict__ gammas,
    const float* __restrict__ etas) {
  __shared__ _Float16 sX[64 * 512];   // 64 KB; row stride 512 halfs, 8-half chunks XOR-swizzled
  const int tid = threadIdx.x;
  const int lane = tid & 63;
  const int wave = tid >> 6;
  const int l16 = lane & 15, quad = lane >> 4;
  const int b0 = blockIdx.x * 64;

  // stage Y fp32 -> fp16 into sX chunks 0..31 (k = 0..255), swizzled
#pragma unroll
  for (int it = 0; it < 16; ++it) {
    int i = it * 256 + tid;
    int row = i >> 6, c4 = i & 63;                  // c4 = which float4 (4 halfs)
    float4 v = *(const float4*)(y + (size_t)(b0 + row) * 256 + c4 * 4);
    int chunk = c4 >> 1, sub = (c4 & 1) * 4;
    int phys = chunk ^ (row & 7);
    half4v h = {(_Float16)v.x, (_Float16)v.y, (_Float16)v.z, (_Float16)v.w};
    *(half4v*)(sX + row * 512 + phys * 8 + sub) = h;
  }
  __syncthreads();

  f32x4 acc[8][4];
#pragma unroll
  for (int im = 0; im < 8; ++im)
#pragma unroll
    for (int jn = 0; jn < 4; ++jn) acc[im][jn] = {0.f, 0.f, 0.f, 0.f};

  // Ay = Y @ Wa^T  (K = 256)
  gemm_phase<8, 256>(Wa, sX, wave, l16, quad, acc);

  // epilogue 0: Ay -> global fp16; x0 = shrink(g0*Ay, e0) -> sX
  {
    float g = gammas[0], e = etas[0];
    __syncthreads();                                 // all waves done reading Y
#pragma unroll
    for (int im = 0; im < 8; ++im) {
      int col = wave * 128 + im * 16 + quad * 4;
#pragma unroll
      for (int jn = 0; jn < 4; ++jn) {
        int row = jn * 16 + l16;
        f32x4 a = acc[im][jn];
        half4v ah = {(_Float16)a[0], (_Float16)a[1], (_Float16)a[2], (_Float16)a[3]};
        *(half4v*)(AyBuf + (size_t)(b0 + row) * 512 + col) = ah;
        half4v xh;
#pragma unroll
        for (int r = 0; r < 4; ++r) xh[r] = (_Float16)shrinkf(g * a[r], e);
        int phys = (col >> 3) ^ (row & 7);
        *(half4v*)(sX + row * 512 + phys * 8 + (col & 7)) = xh;
      }
    }
    __syncthreads();
  }

  // 10 iterations, X resident in LDS
  for (int t = 1; t <= 10; ++t) {
#pragma unroll
    for (int im = 0; im < 8; ++im)
#pragma unroll
      for (int jn = 0; jn < 4; ++jn) acc[im][jn] = {0.f, 0.f, 0.f, 0.f};

    gemm_phase<16, 512>(Wc + (size_t)(t - 1) * 262144, sX, wave, l16, quad, acc);

    float g = gammas[t], e = etas[t];
    half4v ayv[8][4];                                // issue all Ay loads first (hide HBM latency under barrier)
#pragma unroll
    for (int im = 0; im < 8; ++im) {
      int col = wave * 128 + im * 16 + quad * 4;
#pragma unroll
      for (int jn = 0; jn < 4; ++jn) {
        int row = jn * 16 + l16;
        ayv[im][jn] = *(const half4v*)(AyBuf + (size_t)(b0 + row) * 512 + col);
      }
    }
    if (t < 10) {
      __syncthreads();                               // all waves done reading old X
#pragma unroll
      for (int im = 0; im < 8; ++im) {
        int col = wave * 128 + im * 16 + quad * 4;
#pragma unroll
        for (int jn = 0; jn < 4; ++jn) {
          int row = jn * 16 + l16;
          half4v xh;
#pragma unroll
          for (int r = 0; r < 4; ++r)
            xh[r] = (_Float16)shrinkf(acc[im][jn][r] + g * (float)ayv[im][jn][r], e);
          int phys = (col >> 3) ^ (row & 7);
          *(half4v*)(sX + row * 512 + phys * 8 + (col & 7)) = xh;
        }
      }
      __syncthreads();
    } else {
      // final iteration: straight to d_out in fp32
#pragma unroll
      for (int im = 0; im < 8; ++im) {
        int col = wave * 128 + im * 16 + quad * 4;
#pragma unroll
        for (int jn = 0; jn < 4; ++jn) {
          int row = jn * 16 + l16;
          f32x4 o;
#pragma unroll
          for (int r = 0; r < 4; ++r)
            o[r] = shrinkf(acc[im][jn][r] + g * (float)ayv[im][jn][r], e);
          *(f32x4*)(out + (size_t)(b0 + row) * 512 + col) = o;
        }
      }
    }
  }
}

extern "C" void kernel_launch(void* const* d_in, const int* in_sizes, int n_in,
                              void* d_out, int out_size, void* d_ws, size_t ws_size,
                              hipStream_t stream) {
  const float* y      = (const float*)d_in[0];
  const float* A      = (const float*)d_in[1];
  const float* B      = (const float*)d_in[2];
  const float* etas   = (const float*)d_in[3];
  const float* gammas = (const float*)d_in[4];

  char* ws = (char*)d_ws;
  _Float16* Wa = (_Float16*)ws;                       // 262,144 B
  _Float16* Wc = (_Float16*)(ws + 262144);            // 5,242,880 B
  _Float16* Ay = (_Float16*)(ws + 262144 + 5242880);  // 67,108,864 B

  hipLaunchKernelGGL(build_wa, dim3(512), dim3(256), 0, stream, A, Wa);
  hipLaunchKernelGGL(build_wc, dim3(10240), dim3(256), 0, stream, B, gammas, Wc);
  hipLaunchKernelGGL(lista_fused, dim3(1024), dim3(256), 0, stream,
                     y, Wa, Wc, Ay, (float*)d_out, gammas, etas);
}

// Round 3
// 1073.869 us; speedup vs baseline: 1.0577x; 1.0577x over previous
//
#include <hip/hip_runtime.h>
#include <cstdint>
#include <cstddef>

typedef _Float16 half8 __attribute__((ext_vector_type(8)));
typedef _Float16 half4v __attribute__((ext_vector_type(4)));
typedef float f32x4 __attribute__((ext_vector_type(4)));

__device__ __forceinline__ float shrinkf(float v, float eta) {
  float a = fabsf(v) - eta;            // LAMBD = 1.0
  return a > 0.0f ? copysignf(a, v) : 0.0f;
}

// ---------- table builders (verified R1/R2) ----------
__global__ void build_wa(const float* __restrict__ A, _Float16* __restrict__ Wa) {
  int idx = blockIdx.x * 256 + threadIdx.x;     // 131072
  int n = idx >> 8, k = idx & 255;
  int p = n >> 1, c = n & 1, q = k >> 1, d = k & 1;
  const float* A0 = A;
  const float* A1 = A + 256 * 128;
  float v;
  if (c == 0) v = (d == 0) ? A0[p * 128 + q] : -A1[p * 128 + q];
  else        v = (d == 0) ? A1[p * 128 + q] :  A0[p * 128 + q];
  Wa[idx] = (_Float16)v;
}

__global__ void build_wc(const float* __restrict__ B, const float* __restrict__ gammas,
                         _Float16* __restrict__ Wc) {
  int idx = blockIdx.x * 256 + threadIdx.x;     // 2,621,440
  int t = idx >> 18;
  int r = idx & 262143;
  int n = r >> 9, k = r & 511;
  int p = n >> 1, c = n & 1, q = k >> 1, d = k & 1;
  float g = gammas[t + 1];
  const float* B0 = B;
  const float* B1 = B + 256 * 256;
  float eye = (p == q) ? 1.0f : 0.0f;
  float v;
  if (c == 0) v = (d == 0) ? (eye - g * B0[p * 256 + q]) : ( g * B1[p * 256 + q]);
  else        v = (d == 0) ? (     - g * B1[p * 256 + q]) : (eye - g * B0[p * 256 + q]);
  Wc[idx] = (_Float16)v;
}

// ---------- fused GEMM phase ----------
// Wave tile: 64 out-cols (A-operand = W rows, global/L2, prefetched 1 K-step
// ahead) x 64 batch rows (B-operand = X, LDS, XOR-swizzled). acc[im][jn].
// C/D: col(n)=lane&15 = batch row, row(m)=(lane>>4)*4+reg = out-col.
template <int NKS, int LDW>
__device__ __forceinline__ void gemm_phase(const _Float16* __restrict__ W,
                                           const _Float16* sX,
                                           int l16, int quad,
                                           f32x4 (&acc)[4][4]) {
  half8 af[4], afn[4];
  const _Float16* wp = W + (size_t)l16 * LDW + quad * 8;  // W pre-offset by wave
#pragma unroll
  for (int i = 0; i < 4; ++i) af[i] = *(const half8*)(wp + i * 16 * LDW);
#pragma unroll
  for (int ks = 0; ks < NKS; ++ks) {
    half8 xf[4];
#pragma unroll
    for (int j = 0; j < 4; ++j) {
      int row = j * 16 + l16;
      int phys = (ks * 4 + quad) ^ (row & 7);       // XOR chunk swizzle
      xf[j] = *(const half8*)(sX + row * 512 + phys * 8);
    }
    if (ks + 1 < NKS) {
#pragma unroll
      for (int i = 0; i < 4; ++i)
        afn[i] = *(const half8*)(wp + i * 16 * LDW + (ks + 1) * 32);
    }
#pragma unroll
    for (int i = 0; i < 4; ++i)
#pragma unroll
      for (int j = 0; j < 4; ++j)
        acc[i][j] = __builtin_amdgcn_mfma_f32_16x16x32_f16(af[i], xf[j], acc[i][j], 0, 0, 0);
#pragma unroll
    for (int i = 0; i < 4; ++i) af[i] = afn[i];
  }
}

// ---------- fused LISTA ----------
// Block = 512 threads (8 waves), owns 64 batch rows; wave w handles out-cols
// [w*64, w*64+64). X resident in 64 KB LDS across all 11 GEMMs. 2 blocks/CU.
__global__ __launch_bounds__(512, 4) void lista_fused(
    const float* __restrict__ y,
    const _Float16* __restrict__ Wa,
    const _Float16* __restrict__ Wc,
    _Float16* __restrict__ AyBuf,
    float* __restrict__ out,
    const float* __restrict__ gammas,
    const float* __restrict__ etas) {
  __shared__ _Float16 sX[64 * 512];   // 64 KB
  const int tid = threadIdx.x;
  const int lane = tid & 63;
  const int wave = tid >> 6;          // 0..7
  const int l16 = lane & 15, quad = lane >> 4;
  const int b0 = blockIdx.x * 64;

  // stage Y fp32 -> fp16 into sX chunks 0..31 (k = 0..255), swizzled
#pragma unroll
  for (int it = 0; it < 8; ++it) {
    int i = it * 512 + tid;
    int row = i >> 6, c4 = i & 63;
    float4 v = *(const float4*)(y + (size_t)(b0 + row) * 256 + c4 * 4);
    int chunk = c4 >> 1, sub = (c4 & 1) * 4;
    int phys = chunk ^ (row & 7);
    half4v h = {(_Float16)v.x, (_Float16)v.y, (_Float16)v.z, (_Float16)v.w};
    *(half4v*)(sX + row * 512 + phys * 8 + sub) = h;
  }
  __syncthreads();

  f32x4 acc[4][4];
#pragma unroll
  for (int i = 0; i < 4; ++i)
#pragma unroll
    for (int j = 0; j < 4; ++j) acc[i][j] = {0.f, 0.f, 0.f, 0.f};

  // Ay = Y @ Wa^T  (K = 256)
  gemm_phase<8, 256>(Wa + (size_t)wave * 64 * 256, sX, l16, quad, acc);

  // epilogue 0: Ay -> global fp16; x0 = shrink(g0*Ay, e0) -> sX
  {
    float g = gammas[0], e = etas[0];
    __syncthreads();                               // all waves done reading Y
#pragma unroll
    for (int i = 0; i < 4; ++i) {
      int col = wave * 64 + i * 16 + quad * 4;
#pragma unroll
      for (int j = 0; j < 4; ++j) {
        int row = j * 16 + l16;
        f32x4 a = acc[i][j];
        half4v ah = {(_Float16)a[0], (_Float16)a[1], (_Float16)a[2], (_Float16)a[3]};
        *(half4v*)(AyBuf + (size_t)(b0 + row) * 512 + col) = ah;
        half4v xh;
#pragma unroll
        for (int r = 0; r < 4; ++r) xh[r] = (_Float16)shrinkf(g * a[r], e);
        int phys = (col >> 3) ^ (row & 7);
        *(half4v*)(sX + row * 512 + phys * 8 + (col & 7)) = xh;
      }
    }
    __syncthreads();
  }

  // 10 iterations, X resident in LDS
  for (int t = 1; t <= 10; ++t) {
#pragma unroll
    for (int i = 0; i < 4; ++i)
#pragma unroll
      for (int j = 0; j < 4; ++j) acc[i][j] = {0.f, 0.f, 0.f, 0.f};

    gemm_phase<16, 512>(Wc + (size_t)(t - 1) * 262144 + (size_t)wave * 64 * 512,
                        sX, l16, quad, acc);

    float g = gammas[t], e = etas[t];
    half4v ayv[4][4];                              // Ay loads issued before barrier
#pragma unroll
    for (int i = 0; i < 4; ++i) {
      int col = wave * 64 + i * 16 + quad * 4;
#pragma unroll
      for (int j = 0; j < 4; ++j) {
        int row = j * 16 + l16;
        ayv[i][j] = *(const half4v*)(AyBuf + (size_t)(b0 + row) * 512 + col);
      }
    }
    if (t < 10) {
      __syncthreads();                             // all waves done reading old X
#pragma unroll
      for (int i = 0; i < 4; ++i) {
        int col = wave * 64 + i * 16 + quad * 4;
#pragma unroll
        for (int j = 0; j < 4; ++j) {
          int row = j * 16 + l16;
          half4v xh;
#pragma unroll
          for (int r = 0; r < 4; ++r)
            xh[r] = (_Float16)shrinkf(acc[i][j][r] + g * (float)ayv[i][j][r], e);
          int phys = (col >> 3) ^ (row & 7);
          *(half4v*)(sX + row * 512 + phys * 8 + (col & 7)) = xh;
        }
      }
      __syncthreads();
    } else {
      // final iteration: straight to d_out in fp32
#pragma unroll
      for (int i = 0; i < 4; ++i) {
        int col = wave * 64 + i * 16 + quad * 4;
#pragma unroll
        for (int j = 0; j < 4; ++j) {
          int row = j * 16 + l16;
          f32x4 o;
#pragma unroll
          for (int r = 0; r < 4; ++r)
            o[r] = shrinkf(acc[i][j][r] + g * (float)ayv[i][j][r], e);
          *(f32x4*)(out + (size_t)(b0 + row) * 512 + col) = o;
        }
      }
    }
  }
}

extern "C" void kernel_launch(void* const* d_in, const int* in_sizes, int n_in,
                              void* d_out, int out_size, void* d_ws, size_t ws_size,
                              hipStream_t stream) {
  const float* y      = (const float*)d_in[0];
  const float* A      = (const float*)d_in[1];
  const float* B      = (const float*)d_in[2];
  const float* etas   = (const float*)d_in[3];
  const float* gammas = (const float*)d_in[4];

  char* ws = (char*)d_ws;
  _Float16* Wa = (_Float16*)ws;                       // 262,144 B
  _Float16* Wc = (_Float16*)(ws + 262144);            // 5,242,880 B
  _Float16* Ay = (_Float16*)(ws + 262144 + 5242880);  // 67,108,864 B

  hipLaunchKernelGGL(build_wa, dim3(512), dim3(256), 0, stream, A, Wa);
  hipLaunchKernelGGL(build_wc, dim3(10240), dim3(256), 0, stream, B, gammas, Wc);
  hipLaunchKernelGGL(lista_fused, dim3(1024), dim3(512), 0, stream,
                     y, Wa, Wc, Ay, (float*)d_out, gammas, etas);
}